// Round 1
// baseline (208.660 us; speedup 1.0000x reference)
//
#include <hip/hip_runtime.h>
#include <hip/hip_bf16.h>
#include <math.h>

#define N_PTS   2048
#define N_NODES 8192
#define N_CMP   1024
#define K_TOP   32

// Workspace layout (all offsets in bytes):
//   bitsT : uint32_t[N_NODES * 32]      @ 0        (1 MiB)  bit (c&31) of word [n*32 + (c>>5)] = mask[n][c]
//   topval: float  [N_PTS * K_TOP]      @ 1 MiB    (256 KiB) descending per row
//   topidx: int    [N_PTS * K_TOP]      @ 1.25 MiB (256 KiB)
#define OFF_BITS   0
#define OFF_TOPV   (1u << 20)
#define OFF_TOPI   ((1u << 20) + (256u << 10))

// ---------------- Kernel 1: bit-pack the mask (transposed) ----------------
// One wave handles one (node n, 64-column group). Coalesced 256B load + ballot.
__global__ __launch_bounds__(256) void pack_kernel(const int* __restrict__ states,
                                                   unsigned int* __restrict__ bitsT) {
    int t    = threadIdx.x;
    int lane = t & 63;
    int W    = blockIdx.x * 4 + (t >> 6);   // global wave id, 0 .. 8192*16-1
    int n    = W >> 4;
    int cg   = W & 15;                      // 64-column group
    int s    = states[(size_t)n * N_CMP + cg * 64 + lane];
    unsigned long long m = __ballot(s != 0);
    if (lane == 0) {
        bitsT[n * 32 + cg * 2]     = (unsigned int)(m & 0xffffffffull);
        bitsT[n * 32 + cg * 2 + 1] = (unsigned int)(m >> 32);
    }
}

// ---------------- Kernel 2: per-row top-K (descending) ----------------
// One block (256 threads) per row. Each thread caches 32 elements in VGPRs.
#define NEG (-INFINITY)

__global__ __launch_bounds__(256) void topk_kernel(const float* __restrict__ x,
                                                   float* __restrict__ topval,
                                                   int* __restrict__ topidx) {
    int p = blockIdx.x;
    int t = threadIdx.x;
    const float4* row4 = reinterpret_cast<const float4*>(x + (size_t)p * N_NODES);

    // element index of r[j] component e:  j*1024 + t*4 + e
    float4 r[8];
#pragma unroll
    for (int j = 0; j < 8; j++) r[j] = row4[j * 256 + t];

    float lmax = NEG;
    int   lidx = 0;
#define UPD(val, id) do { if ((val) > lmax) { lmax = (val); lidx = (id); } } while (0)
#pragma unroll
    for (int j = 0; j < 8; j++) {
        int base = j * 1024 + (t << 2);
        UPD(r[j].x, base);
        UPD(r[j].y, base + 1);
        UPD(r[j].z, base + 2);
        UPD(r[j].w, base + 3);
    }

    __shared__ float s_val[4];
    __shared__ int   s_idx[4];
    __shared__ float out_v[K_TOP];
    __shared__ int   out_i[K_TOP];

    for (int k = 0; k < K_TOP; k++) {
        // wave-level (max, idx) reduce
        float v = lmax;
        int   i = lidx;
#pragma unroll
        for (int d = 1; d < 64; d <<= 1) {
            float v2 = __shfl_xor(v, d);
            int   i2 = __shfl_xor(i, d);
            if (v2 > v) { v = v2; i = i2; }
        }
        int wave = t >> 6;
        if ((t & 63) == 0) { s_val[wave] = v; s_idx[wave] = i; }
        __syncthreads();
        float gv = s_val[0];
        int   gi = s_idx[0];
#pragma unroll
        for (int w = 1; w < 4; w++) {
            if (s_val[w] > gv) { gv = s_val[w]; gi = s_idx[w]; }
        }
        if (t == 0) { out_v[k] = gv; out_i[k] = gi; }

        // owning thread clears the extracted element and rescans its 32 regs
        if (gi == lidx) {
#pragma unroll
            for (int j = 0; j < 8; j++) {
                int base = j * 1024 + (t << 2);
                if (gi == base)     r[j].x = NEG;
                if (gi == base + 1) r[j].y = NEG;
                if (gi == base + 2) r[j].z = NEG;
                if (gi == base + 3) r[j].w = NEG;
            }
            lmax = NEG; lidx = 0;
#pragma unroll
            for (int j = 0; j < 8; j++) {
                int base = j * 1024 + (t << 2);
                UPD(r[j].x, base);
                UPD(r[j].y, base + 1);
                UPD(r[j].z, base + 2);
                UPD(r[j].w, base + 3);
            }
        }
        __syncthreads();
    }

    if (t < K_TOP) {
        topval[(size_t)p * K_TOP + t] = out_v[t];
        topidx[(size_t)p * K_TOP + t] = out_i[t];
    }
#undef UPD
}

// ---------------- Kernel 3: probe ----------------
// One wave = (row p, 64 columns). Walk top-32 descending; first hit = answer.
__global__ __launch_bounds__(256) void probe_kernel(const float* __restrict__ x,
                                                    const unsigned int* __restrict__ bitsT,
                                                    const float* __restrict__ topval,
                                                    const int* __restrict__ topidx,
                                                    float* __restrict__ out) {
    int t    = threadIdx.x;
    int lane = t & 63;
    int W    = blockIdx.x * 4 + (t >> 6);   // 0 .. 2048*16-1
    int p    = W >> 4;
    int cg   = W & 15;
    int c    = cg * 64 + lane;

    const float* tv = topval + (size_t)p * K_TOP;
    const int*   ti = topidx + (size_t)p * K_TOP;

    float result = 0.0f;     // default: empty column / not found
    bool  done   = false;

#pragma unroll 1
    for (int k = 0; k < K_TOP; k++) {
        int n = __builtin_amdgcn_readfirstlane(ti[k]);   // wave-uniform
        float v = tv[k];
        unsigned int w = bitsT[n * 32 + (c >> 5)];
        bool hit = (w >> (c & 31)) & 1u;
        if (!done && hit) { result = v; done = true; }
        if (__all((int)done)) break;
    }

    if (!__all((int)done)) {
        // Guaranteed-correct fallback: full masked scan for undone lanes.
        const float* row = x + (size_t)p * N_NODES;
        float m = NEG;
        for (int n = 0; n < N_NODES; n++) {
            unsigned int w = bitsT[n * 32 + (c >> 5)];
            if ((w >> (c & 31)) & 1u) m = fmaxf(m, row[n]);
        }
        if (!done) result = (m == NEG) ? 0.0f : m;
    }

    out[(size_t)p * N_CMP + c] = result;
}

// ---------------- launch ----------------
extern "C" void kernel_launch(void* const* d_in, const int* in_sizes, int n_in,
                              void* d_out, int out_size, void* d_ws, size_t ws_size,
                              hipStream_t stream) {
    const float* x      = (const float*)d_in[0];
    const int*   states = (const int*)d_in[1];
    float*       out    = (float*)d_out;

    unsigned int* bitsT  = (unsigned int*)((char*)d_ws + OFF_BITS);
    float*        topval = (float*)((char*)d_ws + OFF_TOPV);
    int*          topidx = (int*)((char*)d_ws + OFF_TOPI);

    // 1) pack mask bits: 8192 nodes x 16 col-groups = 131072 waves / 4 per block
    pack_kernel<<<(N_NODES * (N_CMP / 64)) / 4, 256, 0, stream>>>(states, bitsT);

    // 2) per-row top-32
    topk_kernel<<<N_PTS, 256, 0, stream>>>(x, topval, topidx);

    // 3) probe: 2048 rows x 16 col-groups = 32768 waves / 4 per block
    probe_kernel<<<(N_PTS * (N_CMP / 64)) / 4, 256, 0, stream>>>(x, bitsT, topval, topidx, out);
}

// Round 2
// 146.081 us; speedup vs baseline: 1.4284x; 1.4284x over previous
//
#include <hip/hip_runtime.h>
#include <hip/hip_bf16.h>
#include <math.h>

#define N_PTS   2048
#define N_NODES 8192
#define N_CMP   1024
#define CAP     128     // max list length per row
#define K_MIN   32
#define K_MAX   112

// Workspace layout (bytes):
//   bitsT : uint[N_NODES*32]   @ 0      (1 MiB)   bit (c&31) of word [n*32+(c>>5)] = mask[n][c]
//   topval: float[N_PTS*CAP]   @ 1 MiB  (1 MiB)   descending per row
//   topidx: int  [N_PTS*CAP]   @ 2 MiB  (1 MiB)
//   toplen: int  [N_PTS]       @ 3 MiB  (8 KiB)   -1 => row needs full fallback
#define OFF_BITS 0
#define OFF_TOPV (1u << 20)
#define OFF_TOPI (2u << 20)
#define OFF_LEN  (3u << 20)

__device__ __forceinline__ unsigned int float_to_key(float f) {
    unsigned int b = __float_as_uint(f);
    return (b & 0x80000000u) ? ~b : (b | 0x80000000u);
}
__device__ __forceinline__ float key_to_float(unsigned int k) {
    unsigned int b = (k & 0x80000000u) ? (k ^ 0x80000000u) : ~k;
    return __uint_as_float(b);
}

// ---------------- Kernel 1: bit-pack the mask (transposed) ----------------
__global__ __launch_bounds__(256) void pack_kernel(const int* __restrict__ states,
                                                   unsigned int* __restrict__ bitsT) {
    int t    = threadIdx.x;
    int lane = t & 63;
    int W    = blockIdx.x * 4 + (t >> 6);   // 0 .. 8192*16-1
    int n    = W >> 4;
    int cg   = W & 15;
    int s    = states[(size_t)n * N_CMP + cg * 64 + lane];
    unsigned long long m = __ballot(s != 0);
    if (lane == 0) {
        bitsT[n * 32 + cg * 2]     = (unsigned int)(m & 0xffffffffull);
        bitsT[n * 32 + cg * 2 + 1] = (unsigned int)(m >> 32);
    }
}

// ---------------- Kernel 2: threshold-select + sort per row ----------------
// One block (256 thr) per row; 32 elements/thread as order-preserving uint keys.
__global__ __launch_bounds__(256) void select_kernel(const float* __restrict__ x,
                                                     float* __restrict__ topval,
                                                     int* __restrict__ topidx,
                                                     int* __restrict__ toplen) {
    int p = blockIdx.x;
    int t = threadIdx.x;
    const float4* row4 = reinterpret_cast<const float4*>(x + (size_t)p * N_NODES);

    // element index of key[j*4+e] is j*1024 + t*4 + e
    unsigned int key[32];
#pragma unroll
    for (int j = 0; j < 8; j++) {
        float4 v = row4[j * 256 + t];
        key[j * 4 + 0] = float_to_key(v.x);
        key[j * 4 + 1] = float_to_key(v.y);
        key[j * 4 + 2] = float_to_key(v.z);
        key[j * 4 + 3] = float_to_key(v.w);
    }

    __shared__ unsigned int s_cnt[2][4];
    __shared__ unsigned int s_red[4];
    __shared__ unsigned int s_key[CAP];
    __shared__ int          s_id[CAP];
    __shared__ int          s_num;

    // block max of keys (warm upper bound for bisection)
    unsigned int m = 0;
#pragma unroll
    for (int i = 0; i < 32; i++) m = max(m, key[i]);
#pragma unroll
    for (int d = 1; d < 64; d <<= 1)
        m = max(m, (unsigned int)__shfl_xor((int)m, d));
    if ((t & 63) == 0) s_red[t >> 6] = m;
    __syncthreads();
    unsigned int M = max(max(s_red[0], s_red[1]), max(s_red[2], s_red[3]));
    __syncthreads();

    // bisection for threshold T with count(key >= T) in [K_MIN, K_MAX]
    unsigned int lo = 0, hi = M;
    for (int it = 0; it < 34; ++it) {
        if (hi - lo <= 1) break;
        unsigned int mid;
        if (it == 0) {
            mid = 0xC0200000u;                      // key(2.5f) warm probe
            if (mid >= hi) mid = hi - 1;
            if (mid <= lo) mid = lo + 1;
        } else {
            mid = lo + ((hi - lo) >> 1);
        }
        // block-wide count(key >= mid): ballot per key, no shuffle chains
        int myc = 0;
#pragma unroll
        for (int i = 0; i < 32; i++)
            myc += (int)__popcll(__ballot(key[i] >= mid));
        int par = it & 1;
        if ((t & 63) == 0) s_cnt[par][t >> 6] = (unsigned int)myc;
        __syncthreads();
        int c = (int)(s_cnt[par][0] + s_cnt[par][1] + s_cnt[par][2] + s_cnt[par][3]);
        if (c >= K_MIN) {
            lo = mid;
            if (c <= K_MAX) break;
        } else {
            hi = mid;
        }
    }
    unsigned int T = lo;

    // compact all keys >= T into LDS
    if (t == 0) s_num = 0;
    __syncthreads();
#pragma unroll
    for (int i = 0; i < 32; i++) {
        if (key[i] >= T) {
            int pos = atomicAdd(&s_num, 1);
            if (pos < CAP) {
                s_key[pos] = key[i];
                s_id[pos]  = (i >> 2) * 1024 + (t << 2) + (i & 3);
            }
        }
    }
    __syncthreads();
    int L   = s_num;
    int len = (L > CAP) ? -1 : L;   // pathological (ties) -> row fallback

    // rank-sort descending (broadcast LDS reads; unique ranks via index tiebreak)
    if (len > 0 && t < L) {
        unsigned int mk = s_key[t];
        int          mi = s_id[t];
        int r = 0;
        for (int j = 0; j < L; ++j) {
            unsigned int kj = s_key[j];
            r += (int)((kj > mk) | ((kj == mk) & (j < t)));
        }
        topval[(size_t)p * CAP + r] = key_to_float(mk);
        topidx[(size_t)p * CAP + r] = mi;
    }
    if (t == 0) toplen[p] = len;
}

// ---------------- Kernel 3: probe ----------------
// Block = 4 waves sharing one row p (cgs q*4..q*4+3); list staged in LDS;
// chunk-8 walk with independent prefetched bitsT loads, early exit per chunk.
__global__ __launch_bounds__(256) void probe_kernel(const float* __restrict__ x,
                                                    const unsigned int* __restrict__ bitsT,
                                                    const float* __restrict__ topval,
                                                    const int* __restrict__ topidx,
                                                    const int* __restrict__ toplen,
                                                    float* __restrict__ out) {
    int t    = threadIdx.x;
    int lane = t & 63;
    int wid  = t >> 6;
    int b    = blockIdx.x;          // 0 .. 2048*4-1
    int p    = b >> 2;
    int q    = b & 3;
    int cg   = q * 4 + wid;
    int c    = cg * 64 + lane;
    int w5   = c >> 5;
    int bit  = c & 31;

    __shared__ float s_v[CAP];
    __shared__ int   s_n[CAP];
    __shared__ int   s_len;

    if (t == 0) s_len = toplen[p];
    if (t < CAP) {
        s_v[t] = topval[(size_t)p * CAP + t];
        s_n[t] = topidx[(size_t)p * CAP + t];
    }
    __syncthreads();
    int len = s_len;

    float res  = 0.0f;
    bool  done = false;

    if (len >= 0) {
#pragma unroll 1
        for (int k0 = 0; k0 < len; k0 += 8) {
            int kmax = len - k0;
            if (kmax > 8) kmax = 8;
            unsigned int wb[8];
#pragma unroll
            for (int j = 0; j < 8; j++)
                if (j < kmax) wb[j] = bitsT[s_n[k0 + j] * 32 + w5];
#pragma unroll
            for (int j = 0; j < 8; j++) {
                if (j < kmax) {
                    bool hit = (wb[j] >> bit) & 1u;
                    if (!done && hit) { res = s_v[k0 + j]; done = true; }
                }
            }
            if (__all((int)done)) break;
        }
    }

    if (!done) {
        // exact fallback: full masked scan of the row for this lane (rare)
        const float* row = x + (size_t)p * N_NODES;
        float mm = -INFINITY;
        for (int n = 0; n < N_NODES; n++) {
            unsigned int w = bitsT[n * 32 + w5];
            if ((w >> bit) & 1u) mm = fmaxf(mm, row[n]);
        }
        res = (mm == -INFINITY) ? 0.0f : mm;
    }

    out[(size_t)p * N_CMP + c] = res;
}

// ---------------- launch ----------------
extern "C" void kernel_launch(void* const* d_in, const int* in_sizes, int n_in,
                              void* d_out, int out_size, void* d_ws, size_t ws_size,
                              hipStream_t stream) {
    const float* x      = (const float*)d_in[0];
    const int*   states = (const int*)d_in[1];
    float*       out    = (float*)d_out;

    unsigned int* bitsT  = (unsigned int*)((char*)d_ws + OFF_BITS);
    float*        topval = (float*)((char*)d_ws + OFF_TOPV);
    int*          topidx = (int*)((char*)d_ws + OFF_TOPI);
    int*          toplen = (int*)((char*)d_ws + OFF_LEN);

    pack_kernel<<<(N_NODES * (N_CMP / 64)) / 4, 256, 0, stream>>>(states, bitsT);
    select_kernel<<<N_PTS, 256, 0, stream>>>(x, topval, topidx, toplen);
    probe_kernel<<<N_PTS * 4, 256, 0, stream>>>(x, bitsT, topval, topidx, toplen, out);
}

// Round 4
// 132.539 us; speedup vs baseline: 1.5743x; 1.1022x over previous
//
#include <hip/hip_runtime.h>
#include <hip/hip_bf16.h>
#include <math.h>

#define N_PTS   2048
#define N_NODES 8192
#define N_CMP   1024
#define CAP     128     // max list length per row
#define K_MIN   32
#define K_MAX   112

// Workspace layout (bytes):
//   bitsT : uint[N_NODES*32]   @ 0      (1 MiB)
//   topval: float[N_PTS*CAP]   @ 1 MiB  (1 MiB)
//   topidx: int  [N_PTS*CAP]   @ 2 MiB  (1 MiB)
//   toplen: int  [N_PTS]       @ 3 MiB  (8 KiB)   -1 => row needs full fallback
#define OFF_BITS 0
#define OFF_TOPV (1u << 20)
#define OFF_TOPI (2u << 20)
#define OFF_LEN  (3u << 20)

// bitsT layout (permuted to make the packer ballot-friendly):
//   column c, node n:  g = c>>8 (256-col group), e = c&3, l = (c>>2)&63
//   dword = n*32 + g*8 + e*2 + (l>>5);  bit = l & 31
// Writer: wave handles (n,g); lane loads int4 = states[n][g*256+lane*4 .. +3];
// ballot(e) bit l == column g*256 + l*4 + e.  Consistent with the reader above.

__device__ __forceinline__ unsigned int float_to_key(float f) {
    unsigned int b = __float_as_uint(f);
    return (b & 0x80000000u) ? ~b : (b | 0x80000000u);
}
__device__ __forceinline__ float key_to_float(unsigned int k) {
    unsigned int b = (k & 0x80000000u) ? (k ^ 0x80000000u) : ~k;
    return __uint_as_float(b);
}

__device__ __forceinline__ int col_word_off(int c) {   // dword offset within node stride 32
    return (c >> 8) * 8 + (c & 3) * 2 + (((c >> 2) & 63) >> 5);
}
__device__ __forceinline__ int col_bit(int c) {
    return (c >> 2) & 31;
}

// ---------------- Kernel 1: fused select (blocks 0..N_PTS) + pack (rest) ----
__global__ __launch_bounds__(256) void prep_kernel(const float* __restrict__ x,
                                                   const int4* __restrict__ states4,
                                                   unsigned int* __restrict__ bitsT,
                                                   float* __restrict__ topval,
                                                   int* __restrict__ topidx,
                                                   int* __restrict__ toplen) {
    int b = blockIdx.x;
    int t = threadIdx.x;

    if (b >= N_PTS) {
        // ---- pack: one wave per (node n, 256-col group g) ----
        int lane = t & 63;
        int W = (b - N_PTS) * 4 + (t >> 6);   // 0 .. 8192*4-1
        int n = W >> 2;
        int g = W & 3;
        int4 v = states4[(size_t)n * 256 + g * 64 + lane];
        unsigned long long b0 = __ballot(v.x != 0);
        unsigned long long b1 = __ballot(v.y != 0);
        unsigned long long b2 = __ballot(v.z != 0);
        unsigned long long b3 = __ballot(v.w != 0);
        if (lane == 0) {
            uint4* dst = reinterpret_cast<uint4*>(bitsT + n * 32 + g * 8);
            dst[0] = make_uint4((unsigned)b0, (unsigned)(b0 >> 32),
                                (unsigned)b1, (unsigned)(b1 >> 32));
            dst[1] = make_uint4((unsigned)b2, (unsigned)(b2 >> 32),
                                (unsigned)b3, (unsigned)(b3 >> 32));
        }
        return;
    }

    // ---- select: threshold-select + sort for row p = b ----
    int p = b;
    const float4* row4 = reinterpret_cast<const float4*>(x + (size_t)p * N_NODES);

    // element index of key[j*4+e] is j*1024 + t*4 + e
    unsigned int key[32];
#pragma unroll
    for (int j = 0; j < 8; j++) {
        float4 v = row4[j * 256 + t];
        key[j * 4 + 0] = float_to_key(v.x);
        key[j * 4 + 1] = float_to_key(v.y);
        key[j * 4 + 2] = float_to_key(v.z);
        key[j * 4 + 3] = float_to_key(v.w);
    }

    __shared__ unsigned int s_cnt[2][4];
    __shared__ unsigned int s_red[4];
    __shared__ unsigned int s_key[CAP];
    __shared__ int          s_id[CAP];
    __shared__ int          s_num;

    // block max of keys (upper bound for bisection)
    unsigned int m = 0;
#pragma unroll
    for (int i = 0; i < 32; i++) m = max(m, key[i]);
#pragma unroll
    for (int d = 1; d < 64; d <<= 1)
        m = max(m, (unsigned int)__shfl_xor((int)m, d));
    if ((t & 63) == 0) s_red[t >> 6] = m;
    __syncthreads();
    unsigned int M = max(max(s_red[0], s_red[1]), max(s_red[2], s_red[3]));
    __syncthreads();

    // bisection: find T with count(key >= T) in [K_MIN, K_MAX]
    unsigned int lo = 0, hi = M;
    for (int it = 0; it < 34; ++it) {
        if (hi - lo <= 1) break;
        unsigned int mid;
        if (it == 0) {
            mid = 0xC0200000u;                  // key(2.5f) warm probe (~51 hits on N(0,1))
            if (mid >= hi) mid = hi - 1;
            if (mid <= lo) mid = lo + 1;
        } else {
            mid = lo + ((hi - lo) >> 1);
        }
        int myc = 0;
#pragma unroll
        for (int i = 0; i < 32; i++)
            myc += (int)__popcll(__ballot(key[i] >= mid));
        int par = it & 1;
        if ((t & 63) == 0) s_cnt[par][t >> 6] = (unsigned int)myc;
        __syncthreads();
        int c = (int)(s_cnt[par][0] + s_cnt[par][1] + s_cnt[par][2] + s_cnt[par][3]);
        if (c >= K_MIN) {
            lo = mid;
            if (c <= K_MAX) break;
        } else {
            hi = mid;
        }
    }
    unsigned int T = lo;

    // compact all keys >= T into LDS
    if (t == 0) s_num = 0;
    __syncthreads();
#pragma unroll
    for (int i = 0; i < 32; i++) {
        if (key[i] >= T) {
            int pos = atomicAdd(&s_num, 1);
            if (pos < CAP) {
                s_key[pos] = key[i];
                s_id[pos]  = (i >> 2) * 1024 + (t << 2) + (i & 3);
            }
        }
    }
    __syncthreads();
    int L   = s_num;
    int len = (L > CAP) ? -1 : L;   // pathological ties -> row fallback

    // rank-sort descending (unique ranks via index tiebreak)
    if (len > 0 && t < L) {
        unsigned int mk = s_key[t];
        int          mi = s_id[t];
        int r = 0;
        for (int j = 0; j < L; ++j) {
            unsigned int kj = s_key[j];
            r += (int)((kj > mk) | ((kj == mk) & (j < t)));
        }
        topval[(size_t)p * CAP + r] = key_to_float(mk);
        topidx[(size_t)p * CAP + r] = mi;
    }
    if (t == 0) toplen[p] = len;
}

// ---------------- Kernel 2: probe ----------------
// One block per row; list staged once; wave w walks cgs {i*4+w}, i=0..3.
__global__ __launch_bounds__(256) void probe_kernel(const float* __restrict__ x,
                                                    const unsigned int* __restrict__ bitsT,
                                                    const float* __restrict__ topval,
                                                    const int* __restrict__ topidx,
                                                    const int* __restrict__ toplen,
                                                    float* __restrict__ out) {
    int p    = blockIdx.x;
    int t    = threadIdx.x;
    int lane = t & 63;
    int w    = t >> 6;

    __shared__ float s_v[CAP];
    __shared__ int   s_n[CAP];
    __shared__ int   s_len;

    if (t == 0) s_len = toplen[p];
    if (t < CAP) {
        s_v[t] = topval[(size_t)p * CAP + t];
        s_n[t] = topidx[(size_t)p * CAP + t];
    }
    __syncthreads();
    int len = s_len;

#pragma unroll 1
    for (int i = 0; i < 4; ++i) {
        int cg   = i * 4 + w;            // waves write adjacent 64-col segments
        int c    = cg * 64 + lane;
        int woff = col_word_off(c);
        int bit  = col_bit(c);

        float res  = 0.0f;
        bool  done = false;

        if (len >= 0) {
#pragma unroll 1
            for (int k0 = 0; k0 < len; k0 += 8) {
                int kmax = len - k0;
                if (kmax > 8) kmax = 8;
                unsigned int wb[8];
#pragma unroll
                for (int j = 0; j < 8; j++)
                    if (j < kmax) wb[j] = bitsT[s_n[k0 + j] * 32 + woff];
#pragma unroll
                for (int j = 0; j < 8; j++) {
                    if (j < kmax) {
                        bool hit = (wb[j] >> bit) & 1u;
                        if (!done && hit) { res = s_v[k0 + j]; done = true; }
                    }
                }
                if (__all((int)done)) break;
            }
        }

        if (!done) {
            // exact fallback (essentially never taken; needed for ties / misses)
            const float* row = x + (size_t)p * N_NODES;
            float mm = -INFINITY;
            for (int n = 0; n < N_NODES; n++) {
                unsigned int wd = bitsT[n * 32 + woff];
                if ((wd >> bit) & 1u) mm = fmaxf(mm, row[n]);
            }
            res = (mm == -INFINITY) ? 0.0f : mm;
        }

        out[(size_t)p * N_CMP + c] = res;
    }
}

// ---------------- launch ----------------
extern "C" void kernel_launch(void* const* d_in, const int* in_sizes, int n_in,
                              void* d_out, int out_size, void* d_ws, size_t ws_size,
                              hipStream_t stream) {
    const float* x       = (const float*)d_in[0];
    const int4*  states4 = (const int4*)d_in[1];
    float*       out     = (float*)d_out;

    unsigned int* bitsT  = (unsigned int*)((char*)d_ws + OFF_BITS);
    float*        topval = (float*)((char*)d_ws + OFF_TOPV);
    int*          topidx = (int*)((char*)d_ws + OFF_TOPI);
    int*          toplen = (int*)((char*)d_ws + OFF_LEN);

    // blocks [0, N_PTS): select rows; blocks [N_PTS, N_PTS+8192): pack mask
    prep_kernel<<<N_PTS + N_NODES, 256, 0, stream>>>(x, states4, bitsT,
                                                     topval, topidx, toplen);
    probe_kernel<<<N_PTS, 256, 0, stream>>>(x, bitsT, topval, topidx, toplen, out);
}

// Round 5
// 130.496 us; speedup vs baseline: 1.5990x; 1.0157x over previous
//
#include <hip/hip_runtime.h>
#include <hip/hip_bf16.h>
#include <math.h>

#define N_PTS   2048
#define N_NODES 8192
#define N_CMP   1024
#define CAP     128     // max candidate list length per row
#define K_MIN   32
#define K_MAX   112

// Single fused kernel. Block p handles row p completely:
//   1) load row into 32 keys/thread (order-preserving uint transform)
//   2) bisect threshold T so count(key >= T) in [K_MIN, K_MAX]
//   3) compact + rank-sort candidates (val desc, node id) into LDS
//   4) probe: each wave covers 4 column-groups; walk candidates in chunks
//      of 8, hit-test directly against states[n][c] (L2/L3-resident),
//      first hit in descending order is the masked max. Guaranteed-exact
//      fallback scan for (essentially impossible) misses / ties overflow.
// No workspace used at all.

__device__ __forceinline__ unsigned int float_to_key(float f) {
    unsigned int b = __float_as_uint(f);
    return (b & 0x80000000u) ? ~b : (b | 0x80000000u);
}
__device__ __forceinline__ float key_to_float(unsigned int k) {
    unsigned int b = (k & 0x80000000u) ? (k ^ 0x80000000u) : ~k;
    return __uint_as_float(b);
}

__global__ __launch_bounds__(256) void fused_kernel(const float* __restrict__ x,
                                                    const int* __restrict__ states,
                                                    float* __restrict__ out) {
    int p    = blockIdx.x;
    int t    = threadIdx.x;
    int lane = t & 63;
    int w    = t >> 6;

    const float4* row4 = reinterpret_cast<const float4*>(x + (size_t)p * N_NODES);

    // element index of key[j*4+e] is j*1024 + t*4 + e
    unsigned int key[32];
#pragma unroll
    for (int j = 0; j < 8; j++) {
        float4 v = row4[j * 256 + t];
        key[j * 4 + 0] = float_to_key(v.x);
        key[j * 4 + 1] = float_to_key(v.y);
        key[j * 4 + 2] = float_to_key(v.z);
        key[j * 4 + 3] = float_to_key(v.w);
    }

    __shared__ unsigned int s_cnt[2][4];
    __shared__ unsigned int s_red[4];
    __shared__ unsigned int s_key[CAP];
    __shared__ int          s_id[CAP];
    __shared__ float        s_sv[CAP];   // sorted values (desc)
    __shared__ int          s_sn[CAP];   // sorted node ids
    __shared__ int          s_num;

    // ---- block max of keys (upper bound for bisection) ----
    unsigned int m = 0;
#pragma unroll
    for (int i = 0; i < 32; i++) m = max(m, key[i]);
#pragma unroll
    for (int d = 1; d < 64; d <<= 1)
        m = max(m, (unsigned int)__shfl_xor((int)m, d));
    if (lane == 0) s_red[w] = m;
    __syncthreads();
    unsigned int M = max(max(s_red[0], s_red[1]), max(s_red[2], s_red[3]));
    __syncthreads();

    // ---- bisection: find T with count(key >= T) in [K_MIN, K_MAX] ----
    unsigned int lo = 0, hi = M;
    for (int it = 0; it < 34; ++it) {
        if (hi - lo <= 1) break;
        unsigned int mid;
        if (it == 0) {
            mid = 0xC0200000u;                  // key(2.5f): ~51 hits on N(0,1) rows
            if (mid >= hi) mid = hi - 1;
            if (mid <= lo) mid = lo + 1;
        } else {
            mid = lo + ((hi - lo) >> 1);
        }
        int myc = 0;
#pragma unroll
        for (int i = 0; i < 32; i++)
            myc += (int)__popcll(__ballot(key[i] >= mid));
        int par = it & 1;
        if (lane == 0) s_cnt[par][w] = (unsigned int)myc;
        __syncthreads();
        int c = (int)(s_cnt[par][0] + s_cnt[par][1] + s_cnt[par][2] + s_cnt[par][3]);
        if (c >= K_MIN) {
            lo = mid;
            if (c <= K_MAX) break;
        } else {
            hi = mid;
        }
    }
    unsigned int T = lo;

    // ---- compact keys >= T into LDS ----
    if (t == 0) s_num = 0;
    __syncthreads();
#pragma unroll
    for (int i = 0; i < 32; i++) {
        if (key[i] >= T) {
            int pos = atomicAdd(&s_num, 1);
            if (pos < CAP) {
                s_key[pos] = key[i];
                s_id[pos]  = (i >> 2) * 1024 + (t << 2) + (i & 3);
            }
        }
    }
    __syncthreads();
    int L   = s_num;
    int len = (L > CAP) ? -1 : L;   // pathological ties -> whole-row fallback

    // ---- rank-sort descending into s_sv / s_sn ----
    if (len > 0 && t < L) {
        unsigned int mk = s_key[t];
        int          mi = s_id[t];
        int r = 0;
        for (int j = 0; j < L; ++j) {
            unsigned int kj = s_key[j];
            r += (int)((kj > mk) | ((kj == mk) & (j < t)));
        }
        s_sv[r] = key_to_float(mk);
        s_sn[r] = mi;
    }
    __syncthreads();

    // ---- probe: wave w covers column-groups {i*4+w} ----
    const int* srow_base = states;  // states[n*N_CMP + c]
#pragma unroll 1
    for (int i = 0; i < 4; ++i) {
        int cg = i * 4 + w;          // waves write adjacent 64-col segments
        int c  = cg * 64 + lane;

        float res  = 0.0f;
        bool  done = false;

        if (len >= 0) {
#pragma unroll 1
            for (int k0 = 0; k0 < len; k0 += 8) {
                int kmax = len - k0;
                if (kmax > 8) kmax = 8;
                int sv[8];
#pragma unroll
                for (int j = 0; j < 8; j++) {
                    if (j < kmax) {
                        int n = __builtin_amdgcn_readfirstlane(s_sn[k0 + j]);
                        sv[j] = srow_base[(size_t)n * N_CMP + c];   // coalesced 256B
                    }
                }
#pragma unroll
                for (int j = 0; j < 8; j++) {
                    if (j < kmax) {
                        bool hit = (sv[j] != 0);
                        if (!done && hit) { res = s_sv[k0 + j]; done = true; }
                    }
                }
                if (__all((int)done)) break;
            }
        }

        if (!done) {
            // exact fallback: masked scan of full column (P(taken) ~ 2^-32/pair)
            const float* row = x + (size_t)p * N_NODES;
            float mm = -INFINITY;
            for (int n = 0; n < N_NODES; n++) {
                if (srow_base[(size_t)n * N_CMP + c] != 0) mm = fmaxf(mm, row[n]);
            }
            res = (mm == -INFINITY) ? 0.0f : mm;
        }

        out[(size_t)p * N_CMP + c] = res;
    }
}

// ---------------- launch ----------------
extern "C" void kernel_launch(void* const* d_in, const int* in_sizes, int n_in,
                              void* d_out, int out_size, void* d_ws, size_t ws_size,
                              hipStream_t stream) {
    const float* x      = (const float*)d_in[0];
    const int*   states = (const int*)d_in[1];
    float*       out    = (float*)d_out;

    fused_kernel<<<N_PTS, 256, 0, stream>>>(x, states, out);
}